// Round 11
// baseline (44.598 us; speedup 1.0000x reference)
//
#include <hip/hip_runtime.h>
#include <hip/hip_bf16.h>
#include <stdint.h>

#define B_ROWS 8192
#define D_DIM  128
#define NCR    8               // column ranges (1024 cols each)
#define STEPS  16              // 64-col steps per range
#define NSLAB  32              // NCR x 4 waves

// zn is pre-scaled by SCALE = sqrt(2*log2(e)) so that the MFMA dot product
// directly equals 2*log2(e)*cos = log2(e^sim), sim = cos/tau, tau = 0.5.
// Then exp2(acc) = e^sim (<= e^2, fp32-safe) and pos = sim = acc*ln2.
#define SCALE  1.6986436f
#define LN2    0.69314718f

typedef __attribute__((ext_vector_type(8))) __bf16 bf16x8;
typedef __attribute__((ext_vector_type(4))) float  f32x4;

typedef __attribute__((address_space(3))) uint32_t lds_u32;
typedef __attribute__((address_space(1))) const uint32_t glb_u32;

__device__ __forceinline__ float fast_exp2(float x) {
    float r;
    asm("v_exp_f32 %0, %1" : "=v"(r) : "v"(x));
    return r;
}

// ---------------- Kernel 1: l2-normalize rows, scale, cast to bf16 ----------
__global__ void k_norm(const float* __restrict__ z, __hip_bfloat16* __restrict__ zn) {
    int row  = blockIdx.x * 4 + (threadIdx.x >> 6);
    int lane = threadIdx.x & 63;
    const float2 v = reinterpret_cast<const float2*>(z + (size_t)row * D_DIM)[lane];
    float ss = v.x * v.x + v.y * v.y;
    #pragma unroll
    for (int m = 1; m < 64; m <<= 1) ss += __shfl_xor(ss, m);
    float inv = SCALE * rsqrtf(fmaxf(ss, 1e-12f));
    __hip_bfloat162 o;
    o.x = __float2bfloat16(v.x * inv);
    o.y = __float2bfloat16(v.y * inv);
    reinterpret_cast<__hip_bfloat162*>(zn + (size_t)row * D_DIM)[lane] = o;
}

// ---------------- Kernel 2: similarity + fused exp row-sums -----------------
// 1024 blocks (~3 resident/CU), 256 thr = 4 waves. Block = 64 rows x 1024
// cols. Wave = ALL 64 rows x a PRIVATE 16-col slice per 64-col step ->
// every B column is ds_read exactly ONCE (redundancy 1); A in registers.
// B double-buffered in LDS (global_load_lds + XOR swizzle, validated R4-R10),
// sync-per-step prefetch (R5/R9 proven). Per-wave output slab (no reduce).
__global__ __launch_bounds__(256, 3) void k_sim(const __bf16* __restrict__ zn,
                                                float* __restrict__ s_partial,
                                                float* __restrict__ pos) {
    __shared__ __align__(16) char sB[2][16384];

    const int tid  = threadIdx.x;
    const int lane = tid & 63;
    const int l15  = lane & 15;
    const int lg   = lane >> 4;          // 0..3
    const int w    = tid >> 6;           // 0..3 : col slice [w*16, +16) per step
    const int rb   = blockIdx.x >> 3;    // 0..127  (64-row tile)
    const int cr   = blockIdx.x & 7;     // 0..7    (1024-col range)
    const int R0   = rb * 64;
    const int C0   = cr * 1024;

    // stage one 64-col B tile (16 KB): 4x 16B per thread, linear LDS dest,
    // inverse-XOR global source (involution on 16B units, row&7)
    auto stage = [&](int gColBase, char* dst) {
        #pragma unroll
        for (int q = 0; q < 4; ++q) {
            int slot = q * 256 + tid;        // 0..1023
            int row  = slot >> 4;            // 0..63
            int u    = slot & 15;
            const __bf16* g = zn + (size_t)(gColBase + row) * D_DIM + ((u ^ (row & 7)) << 3);
            __builtin_amdgcn_global_load_lds((glb_u32*)g, (lds_u32*)(dst + slot * 16), 16, 0, 0);
        }
    };

    stage(C0, sB[0]);                    // first B tile in flight

    // ---- A fragments: global -> registers (16 x bf16x8 = 64 VGPR)
    bf16x8 afr[4][4];
    #pragma unroll
    for (int t = 0; t < 4; ++t)
        #pragma unroll
        for (int ks = 0; ks < 4; ++ks) {
            int row = R0 + t * 16 + l15;
            afr[t][ks] = *reinterpret_cast<const bf16x8*>(
                zn + (size_t)row * D_DIM + ks * 32 + lg * 8);
        }

    float srow[4][4];
    #pragma unroll
    for (int t = 0; t < 4; ++t)
        #pragma unroll
        for (int r = 0; r < 4; ++r) srow[t][r] = 0.f;

    __syncthreads();                     // B tile 0 + A loads landed

    #pragma unroll 1
    for (int s = 0; s < STEPS; ++s) {
        if (s + 1 < STEPS)
            stage(C0 + (s + 1) * 64, sB[(s + 1) & 1]);   // prefetch next

        // this wave's PRIVATE 16-col B fragment (4 x ds_read_b128, once)
        const char* bb = sB[s & 1];
        bf16x8 bfr[4];
        #pragma unroll
        for (int ks = 0; ks < 4; ++ks) {
            int row = w * 16 + l15;
            int kb  = ks * 64 + lg * 16;
            bfr[ks] = *reinterpret_cast<const bf16x8*>(
                bb + row * 256 + (kb ^ ((row & 7) << 4)));
        }

        const int fragCol = C0 + s * 64 + w * 16;
        #pragma unroll
        for (int t = 0; t < 4; ++t) {
            f32x4 acc = {0.f, 0.f, 0.f, 0.f};
            #pragma unroll
            for (int ks = 0; ks < 4; ++ks)
                acc = __builtin_amdgcn_mfma_f32_16x16x32_bf16(afr[t][ks], bfr[ks], acc, 0, 0, 0);

            const int fragRow = R0 + t * 16;
            if (fragRow == fragCol) {        // diagonal frag (wave-uniform)
                const int col = fragCol + l15;
                #pragma unroll
                for (int r = 0; r < 4; ++r) {
                    int row = fragRow + lg * 4 + r;
                    float e = fast_exp2(acc[r]);                      // e^sim
                    if (col == row) e = 0.f;                          // self
                    if (col == (row ^ 1)) pos[row] = acc[r] * LN2;    // partner
                    srow[t][r] += e;
                }
            } else {
                #pragma unroll
                for (int r = 0; r < 4; ++r)
                    srow[t][r] += fast_exp2(acc[r]);
            }
        }
        __syncthreads();   // prefetched tile landed; current buffer reusable
    }

    // ---- reduce over the 16 lanes sharing a row; per-wave slab store
    #pragma unroll
    for (int t = 0; t < 4; ++t)
        #pragma unroll
        for (int r = 0; r < 4; ++r) {
            float v = srow[t][r];
            v += __shfl_xor(v, 1);
            v += __shfl_xor(v, 2);
            v += __shfl_xor(v, 4);
            v += __shfl_xor(v, 8);
            if (l15 == 0) {
                int row = t * 16 + lg * 4 + r;
                s_partial[(size_t)(cr * 4 + w) * B_ROWS + R0 + row] = v;
            }
        }
}

// ---------------- Kernel 3: per-row loss, per-block partial sums ------------
__global__ void k_loss_partial(const float* __restrict__ sp,
                               const float* __restrict__ pos,
                               float* __restrict__ part) {
    int i = blockIdx.x * 256 + threadIdx.x;
    float ssum = 0.f;
    #pragma unroll
    for (int c = 0; c < NSLAB; ++c) ssum += sp[(size_t)c * B_ROWS + i];
    float v = logf(ssum) - pos[i];
    #pragma unroll
    for (int m = 1; m < 64; m <<= 1) v += __shfl_xor(v, m);
    __shared__ float ls[4];
    if ((threadIdx.x & 63) == 0) ls[threadIdx.x >> 6] = v;
    __syncthreads();
    if (threadIdx.x == 0) part[blockIdx.x] = ls[0] + ls[1] + ls[2] + ls[3];
}

// ---------------- Kernel 4: final reduce ------------------------------------
__global__ void k_final(const float* __restrict__ part, float* __restrict__ out) {
    float v = (threadIdx.x < (B_ROWS / 256)) ? part[threadIdx.x] : 0.f;
    #pragma unroll
    for (int m = 1; m < 64; m <<= 1) v += __shfl_xor(v, m);
    if (threadIdx.x == 0) out[0] = v * (1.0f / (float)B_ROWS);
}

extern "C" void kernel_launch(void* const* d_in, const int* in_sizes, int n_in,
                              void* d_out, int out_size, void* d_ws, size_t ws_size,
                              hipStream_t stream) {
    const float* z = (const float*)d_in[0];
    float* out = (float*)d_out;

    char* ws = (char*)d_ws;
    __hip_bfloat16* zn = (__hip_bfloat16*)ws;                              // 2 MB
    float* s_partial = (float*)(ws + (size_t)B_ROWS * D_DIM * 2);          // 1 MB
    float* pos  = (float*)((char*)s_partial + (size_t)NSLAB * B_ROWS * 4); // 32 KB
    float* part = (float*)((char*)pos + (size_t)B_ROWS * 4);               // 128 B

    // 1) normalize + scale + bf16 cast
    k_norm<<<B_ROWS / 4, 256, 0, stream>>>(z, zn);

    // 2) similarity: 128 row-tiles x 8 col-ranges = 1024 blocks, 256 thr
    k_sim<<<128 * NCR, 256, 0, stream>>>((const __bf16*)zn, s_partial, pos);

    // 3) per-row loss -> 32 block partials
    k_loss_partial<<<B_ROWS / 256, 256, 0, stream>>>(s_partial, pos, part);

    // 4) final scalar
    k_final<<<1, 64, 0, stream>>>(part, out);
}

// Round 12
// 43.976 us; speedup vs baseline: 1.0142x; 1.0142x over previous
//
#include <hip/hip_runtime.h>
#include <hip/hip_bf16.h>
#include <stdint.h>

#define B_ROWS 8192
#define D_DIM  128
#define NSLAB  32              // 32 wave-column-ranges of 256 cols
#define WSTEPS 16              // 16-col steps per wave

// zn is pre-scaled by SCALE = sqrt(2*log2(e)): MFMA dot = log2(e^sim),
// sim = cos/tau (tau=0.5). exp2(acc) = e^sim <= e^2; pos = acc*ln2. (R11-validated)
#define SCALE  1.6986436f
#define LN2    0.69314718f

typedef __attribute__((ext_vector_type(8))) __bf16 bf16x8;
typedef __attribute__((ext_vector_type(4))) float  f32x4;

typedef __attribute__((address_space(3))) uint32_t lds_u32;
typedef __attribute__((address_space(1))) const uint32_t glb_u32;

__device__ __forceinline__ float fast_exp2(float x) {
    float r;
    asm("v_exp_f32 %0, %1" : "=v"(r) : "v"(x));
    return r;
}

// ---------------- Kernel 1: l2-normalize rows, scale, cast to bf16 ----------
__global__ void k_norm(const float* __restrict__ z, __hip_bfloat16* __restrict__ zn) {
    int row  = blockIdx.x * 4 + (threadIdx.x >> 6);
    int lane = threadIdx.x & 63;
    const float2 v = reinterpret_cast<const float2*>(z + (size_t)row * D_DIM)[lane];
    float ss = v.x * v.x + v.y * v.y;
    #pragma unroll
    for (int m = 1; m < 64; m <<= 1) ss += __shfl_xor(ss, m);
    float inv = SCALE * rsqrtf(fmaxf(ss, 1e-12f));
    __hip_bfloat162 o;
    o.x = __float2bfloat16(v.x * inv);
    o.y = __float2bfloat16(v.y * inv);
    reinterpret_cast<__hip_bfloat162*>(zn + (size_t)row * D_DIM)[lane] = o;
}

// ---------------- Kernel 2: BARRIER-FREE similarity + fused exp row-sums ----
// 512 blocks x 512 thr; waves fully independent (NO __syncthreads in kernel).
// Wave = 64 rows x 256 cols: A in regs (64 VGPR); B staged 16 cols (4 KB) at
// a time into the wave's PRIVATE LDS region (2 x 4 KB double buffer) via
// global_load_lds. Per-wave counted wait: the end-of-iter vmcnt(0) covers
// loads issued one full compute phase earlier -> near-zero stall, no convoy.
// XOR swizzle scheme on 16B units (validated R4-R11).
__global__ __launch_bounds__(512, 3) void k_sim(const __bf16* __restrict__ zn,
                                                float* __restrict__ s_partial,
                                                float* __restrict__ pos) {
    __shared__ __align__(16) char smem[8][8192];   // per-wave 2 x 4 KB

    const int tid  = threadIdx.x;
    const int lane = tid & 63;
    const int l15  = lane & 15;
    const int lg   = lane >> 4;          // 0..3
    const int w    = tid >> 6;           // 0..7
    const int rg   = blockIdx.x >> 2;    // 0..127 (64-row group)
    const int cq   = blockIdx.x & 3;     // 0..3
    const int R0   = rg * 64;
    const int slab = cq * 8 + w;         // 0..31 : wave's 256-col range
    const int C0   = slab * 256;

    char* sPriv = smem[w];

    // stage 16 B-cols (4 KB) into private buffer buf: 4 wave-level
    // global_load_lds (uniform LDS base + lane*16), inverse-XOR global src
    auto stage = [&](int colBase, int buf) {
        #pragma unroll
        for (int q = 0; q < 4; ++q) {
            int rowl = q * 4 + lg;                       // 0..15 within slice
            const __bf16* g = zn + (size_t)(colBase + rowl) * D_DIM
                                 + ((l15 ^ (rowl & 7)) << 3);
            __builtin_amdgcn_global_load_lds((glb_u32*)g,
                (lds_u32*)(sPriv + buf * 4096 + q * 1024), 16, 0, 0);
        }
    };

    stage(C0, 0);                        // first B slice in flight

    // A fragments: global -> registers (16 x bf16x8 = 64 VGPR)
    bf16x8 afr[4][4];
    #pragma unroll
    for (int t = 0; t < 4; ++t)
        #pragma unroll
        for (int ks = 0; ks < 4; ++ks) {
            int row = R0 + t * 16 + l15;
            afr[t][ks] = *reinterpret_cast<const bf16x8*>(
                zn + (size_t)row * D_DIM + ks * 32 + lg * 8);
        }
    asm volatile("s_waitcnt vmcnt(0)" ::: "memory");   // afr + slice 0 landed
    __builtin_amdgcn_sched_barrier(0);

    float srow[4][4];
    #pragma unroll
    for (int t = 0; t < 4; ++t)
        #pragma unroll
        for (int r = 0; r < 4; ++r) srow[t][r] = 0.f;

    #pragma unroll 1
    for (int s = 0; s < WSTEPS; ++s) {
        // issue next slice into the buffer whose reads were consumed last iter
        if (s + 1 < WSTEPS) stage(C0 + (s + 1) * 16, (s + 1) & 1);

        // this wave's private 16-col B fragment (4 x ds_read_b128)
        const char* bb = sPriv + (s & 1) * 4096;
        bf16x8 bfr[4];
        #pragma unroll
        for (int ks = 0; ks < 4; ++ks) {
            int kb = ks * 64 + lg * 16;
            bfr[ks] = *reinterpret_cast<const bf16x8*>(
                bb + l15 * 256 + (kb ^ ((l15 & 7) << 4)));
        }

        const int fragCol = C0 + s * 16;
        #pragma unroll
        for (int t = 0; t < 4; ++t) {
            f32x4 acc = {0.f, 0.f, 0.f, 0.f};
            #pragma unroll
            for (int ks = 0; ks < 4; ++ks)
                acc = __builtin_amdgcn_mfma_f32_16x16x32_bf16(afr[t][ks], bfr[ks], acc, 0, 0, 0);

            const int fragRow = R0 + t * 16;
            if (fragRow == fragCol) {        // diagonal frag (wave-uniform)
                const int col = fragCol + l15;
                #pragma unroll
                for (int r = 0; r < 4; ++r) {
                    int row = fragRow + lg * 4 + r;
                    float e = fast_exp2(acc[r]);                      // e^sim
                    if (col == row) e = 0.f;                          // self
                    if (col == (row ^ 1)) pos[row] = acc[r] * LN2;    // partner
                    srow[t][r] += e;
                }
            } else {
                #pragma unroll
                for (int r = 0; r < 4; ++r)
                    srow[t][r] += fast_exp2(acc[r]);
            }
        }

        // wave-private wait: slice s+1 (issued at top, ~1 compute phase ago)
        asm volatile("s_waitcnt vmcnt(0)" ::: "memory");
        __builtin_amdgcn_sched_barrier(0);
    }

    // reduce over the 16 lanes sharing a row; per-wave slab store (no LDS)
    #pragma unroll
    for (int t = 0; t < 4; ++t)
        #pragma unroll
        for (int r = 0; r < 4; ++r) {
            float v = srow[t][r];
            v += __shfl_xor(v, 1);
            v += __shfl_xor(v, 2);
            v += __shfl_xor(v, 4);
            v += __shfl_xor(v, 8);
            if (l15 == 0)
                s_partial[(size_t)slab * B_ROWS + R0 + t * 16 + lg * 4 + r] = v;
        }
}

// ---------------- Kernel 3: per-row loss, per-block partial sums ------------
__global__ void k_loss_partial(const float* __restrict__ sp,
                               const float* __restrict__ pos,
                               float* __restrict__ part) {
    int i = blockIdx.x * 256 + threadIdx.x;
    float ssum = 0.f;
    #pragma unroll
    for (int c = 0; c < NSLAB; ++c) ssum += sp[(size_t)c * B_ROWS + i];
    float v = logf(ssum) - pos[i];
    #pragma unroll
    for (int m = 1; m < 64; m <<= 1) v += __shfl_xor(v, m);
    __shared__ float ls[4];
    if ((threadIdx.x & 63) == 0) ls[threadIdx.x >> 6] = v;
    __syncthreads();
    if (threadIdx.x == 0) part[blockIdx.x] = ls[0] + ls[1] + ls[2] + ls[3];
}

// ---------------- Kernel 4: final reduce ------------------------------------
__global__ void k_final(const float* __restrict__ part, float* __restrict__ out) {
    float v = (threadIdx.x < (B_ROWS / 256)) ? part[threadIdx.x] : 0.f;
    #pragma unroll
    for (int m = 1; m < 64; m <<= 1) v += __shfl_xor(v, m);
    if (threadIdx.x == 0) out[0] = v * (1.0f / (float)B_ROWS);
}

extern "C" void kernel_launch(void* const* d_in, const int* in_sizes, int n_in,
                              void* d_out, int out_size, void* d_ws, size_t ws_size,
                              hipStream_t stream) {
    const float* z = (const float*)d_in[0];
    float* out = (float*)d_out;

    char* ws = (char*)d_ws;
    __hip_bfloat16* zn = (__hip_bfloat16*)ws;                              // 2 MB
    float* s_partial = (float*)(ws + (size_t)B_ROWS * D_DIM * 2);          // 1 MB
    float* pos  = (float*)((char*)s_partial + (size_t)NSLAB * B_ROWS * 4); // 32 KB
    float* part = (float*)((char*)pos + (size_t)B_ROWS * 4);               // 128 B

    // 1) normalize + scale + bf16 cast
    k_norm<<<B_ROWS / 4, 256, 0, stream>>>(z, zn);

    // 2) barrier-free similarity: 128 row-groups x 4 = 512 blocks, 512 thr
    k_sim<<<512, 512, 0, stream>>>((const __bf16*)zn, s_partial, pos);

    // 3) per-row loss -> 32 block partials
    k_loss_partial<<<B_ROWS / 256, 256, 0, stream>>>(s_partial, pos, part);

    // 4) final scalar
    k_final<<<1, 64, 0, stream>>>(part, out);
}

// Round 13
// 38.133 us; speedup vs baseline: 1.1695x; 1.1532x over previous
//
#include <hip/hip_runtime.h>
#include <hip/hip_bf16.h>
#include <stdint.h>

#define B_ROWS 8192
#define D_DIM  128
#define NSLAB  8               // 8 column ranges of 1024 cols
#define STEPS  16              // 64-col steps per block

// zn is pre-scaled by SCALE = sqrt(2*log2(e)): MFMA dot = log2(e^sim),
// sim = cos/tau (tau=0.5). exp2(acc) = e^sim <= e^2; pos = acc*ln2.
// Validated R11/R12 (absmax 0).
#define SCALE  1.6986436f
#define LN2    0.69314718f

typedef __attribute__((ext_vector_type(8))) __bf16 bf16x8;
typedef __attribute__((ext_vector_type(4))) float  f32x4;

typedef __attribute__((address_space(3))) uint32_t lds_u32;
typedef __attribute__((address_space(1))) const uint32_t glb_u32;

__device__ __forceinline__ float fast_exp2(float x) {
    float r;
    asm("v_exp_f32 %0, %1" : "=v"(r) : "v"(x));
    return r;
}

// ---------------- Kernel 1: l2-normalize rows, scale, cast to bf16 ----------
__global__ void k_norm(const float* __restrict__ z, __hip_bfloat16* __restrict__ zn) {
    int row  = blockIdx.x * 4 + (threadIdx.x >> 6);
    int lane = threadIdx.x & 63;
    const float2 v = reinterpret_cast<const float2*>(z + (size_t)row * D_DIM)[lane];
    float ss = v.x * v.x + v.y * v.y;
    #pragma unroll
    for (int m = 1; m < 64; m <<= 1) ss += __shfl_xor(ss, m);
    float inv = SCALE * rsqrtf(fmaxf(ss, 1e-12f));
    __hip_bfloat162 o;
    o.x = __float2bfloat16(v.x * inv);
    o.y = __float2bfloat16(v.y * inv);
    reinterpret_cast<__hip_bfloat162*>(zn + (size_t)row * D_DIM)[lane] = o;
}

// ---------------- Kernel 2: similarity + fused exp row-sums -----------------
// 1024 blocks = 4/CU, 256 thr = 4 waves (2 row x 2 col) -> FOUR independent
// barrier domains per CU at 16 waves/CU: one block's barrier/stage stall is
// covered by the other three (m114 cross-block overlap). Wave = 32 rows x
// 32 cols/step. A in regs (32 VGPR); B 64-col tiles double-buffered in LDS
// (global_load_lds + XOR swizzle + sync-per-step prefetch, proven R5/R9).
// VGPR must stay <= 128 for 4 waves/SIMD: __launch_bounds__(256, 4).
__global__ __launch_bounds__(256, 4) void k_sim(const __bf16* __restrict__ zn,
                                                float* __restrict__ s_partial,
                                                float* __restrict__ pos) {
    __shared__ __align__(16) char sB[2][16384];
    __shared__ float red[64][2];

    const int tid  = threadIdx.x;
    const int lane = tid & 63;
    const int l15  = lane & 15;
    const int lg   = lane >> 4;          // 0..3
    const int w    = tid >> 6;           // 0..3
    const int wr   = w >> 1;             // 0..1 : rows [wr*32, +32)
    const int wc   = w & 1;              // 0..1 : cols [wc*32, +32) within step
    const int rb   = blockIdx.x >> 3;    // 0..127  (64-row tile)
    const int cr   = blockIdx.x & 7;     // 0..7    (1024-col range)
    const int R0   = rb * 64;
    const int C0   = cr * 1024;

    // stage one 64-col B tile (16 KB): 4x 16B per thread, linear LDS dest,
    // inverse-XOR global source (involution on 16B units, row&7)
    auto stage = [&](int gColBase, char* dst) {
        #pragma unroll
        for (int q = 0; q < 4; ++q) {
            int slot = q * 256 + tid;        // 0..1023
            int row  = slot >> 4;            // 0..63
            int u    = slot & 15;
            const __bf16* g = zn + (size_t)(gColBase + row) * D_DIM + ((u ^ (row & 7)) << 3);
            __builtin_amdgcn_global_load_lds((glb_u32*)g, (lds_u32*)(dst + slot * 16), 16, 0, 0);
        }
    };

    stage(C0, sB[0]);                    // first B tile in flight

    // ---- A fragments: global -> registers (8 x bf16x8 = 32 VGPR)
    bf16x8 afr[2][4];
    #pragma unroll
    for (int t = 0; t < 2; ++t)
        #pragma unroll
        for (int ks = 0; ks < 4; ++ks) {
            int row = R0 + wr * 32 + t * 16 + l15;
            afr[t][ks] = *reinterpret_cast<const bf16x8*>(
                zn + (size_t)row * D_DIM + ks * 32 + lg * 8);
        }

    float srow[2][4];
    #pragma unroll
    for (int t = 0; t < 2; ++t)
        #pragma unroll
        for (int r = 0; r < 4; ++r) srow[t][r] = 0.f;

    __syncthreads();                     // B tile 0 + A loads landed

    #pragma unroll 1
    for (int s = 0; s < STEPS; ++s) {
        if (s + 1 < STEPS)
            stage(C0 + (s + 1) * 64, sB[(s + 1) & 1]);   // prefetch next

        const char* bb = sB[s & 1];
        bf16x8 bfr[2][4];
        #pragma unroll
        for (int cs = 0; cs < 2; ++cs)
            #pragma unroll
            for (int ks = 0; ks < 4; ++ks) {
                int row = wc * 32 + cs * 16 + l15;
                int kb  = ks * 64 + lg * 16;
                bfr[cs][ks] = *reinterpret_cast<const bf16x8*>(
                    bb + row * 256 + (kb ^ ((row & 7) << 4)));
            }

        #pragma unroll
        for (int t = 0; t < 2; ++t)
            #pragma unroll
            for (int cs = 0; cs < 2; ++cs) {
                f32x4 acc = {0.f, 0.f, 0.f, 0.f};
                #pragma unroll
                for (int ks = 0; ks < 4; ++ks)
                    acc = __builtin_amdgcn_mfma_f32_16x16x32_bf16(afr[t][ks], bfr[cs][ks], acc, 0, 0, 0);

                const int fragRow = R0 + wr * 32 + t * 16;
                const int fragCol = C0 + s * 64 + wc * 32 + cs * 16;
                if (fragRow == fragCol) {        // diagonal frag (wave-uniform)
                    const int col = fragCol + l15;
                    #pragma unroll
                    for (int r = 0; r < 4; ++r) {
                        int row = fragRow + lg * 4 + r;
                        float e = fast_exp2(acc[r]);                     // e^sim
                        if (col == row) e = 0.f;                         // self
                        if (col == (row ^ 1)) pos[row] = acc[r] * LN2;   // partner
                        srow[t][r] += e;
                    }
                } else {
                    #pragma unroll
                    for (int r = 0; r < 4; ++r)
                        srow[t][r] += fast_exp2(acc[r]);
                }
            }
        __syncthreads();   // prefetched tile landed; current buffer reusable
    }

    // ---- reduction: 16 lanes sharing a row -> cross-wave (wc) via LDS
    #pragma unroll
    for (int t = 0; t < 2; ++t)
        #pragma unroll
        for (int r = 0; r < 4; ++r) {
            float v = srow[t][r];
            v += __shfl_xor(v, 1);
            v += __shfl_xor(v, 2);
            v += __shfl_xor(v, 4);
            v += __shfl_xor(v, 8);
            if (l15 == 0) red[wr * 32 + t * 16 + lg * 4 + r][wc] = v;
        }
    __syncthreads();
    if (tid < 64)
        s_partial[(size_t)cr * B_ROWS + R0 + tid] = red[tid][0] + red[tid][1];
}

// ---------------- Kernel 3: fused per-row loss + final reduce (1 block) -----
__global__ __launch_bounds__(1024) void k_loss(const float* __restrict__ sp,
                                               const float* __restrict__ pos,
                                               float* __restrict__ out) {
    float acc = 0.f;
    #pragma unroll
    for (int b = 0; b < B_ROWS / 1024; ++b) {
        int i = b * 1024 + threadIdx.x;
        float ssum = 0.f;
        #pragma unroll
        for (int c = 0; c < NSLAB; ++c) ssum += sp[(size_t)c * B_ROWS + i];
        acc += logf(ssum) - pos[i];
    }
    #pragma unroll
    for (int m = 1; m < 64; m <<= 1) acc += __shfl_xor(acc, m);
    __shared__ float ls[16];
    if ((threadIdx.x & 63) == 0) ls[threadIdx.x >> 6] = acc;
    __syncthreads();
    if (threadIdx.x < 64) {
        float v = (threadIdx.x < 16) ? ls[threadIdx.x] : 0.f;
        #pragma unroll
        for (int m = 1; m < 16; m <<= 1) v += __shfl_xor(v, m);
        if (threadIdx.x == 0) out[0] = v * (1.0f / (float)B_ROWS);
    }
}

extern "C" void kernel_launch(void* const* d_in, const int* in_sizes, int n_in,
                              void* d_out, int out_size, void* d_ws, size_t ws_size,
                              hipStream_t stream) {
    const float* z = (const float*)d_in[0];
    float* out = (float*)d_out;

    char* ws = (char*)d_ws;
    __hip_bfloat16* zn = (__hip_bfloat16*)ws;                              // 2 MB
    float* s_partial = (float*)(ws + (size_t)B_ROWS * D_DIM * 2);          // 256 KB
    float* pos  = (float*)((char*)s_partial + (size_t)NSLAB * B_ROWS * 4); // 32 KB

    // 1) normalize + scale + bf16 cast
    k_norm<<<B_ROWS / 4, 256, 0, stream>>>(z, zn);

    // 2) similarity: 128 row-tiles x 8 col-ranges = 1024 blocks (4/CU), 256 thr
    k_sim<<<128 * NSLAB, 256, 0, stream>>>((const __bf16*)zn, s_partial, pos);

    // 3) fused per-row loss + mean (single block)
    k_loss<<<1, 1024, 0, stream>>>(s_partial, pos, out);
}

// Round 15
// 31.494 us; speedup vs baseline: 1.4161x; 1.2108x over previous
//
#include <hip/hip_runtime.h>
#include <hip/hip_bf16.h>
#include <hip/hip_fp8.h>
#include <stdint.h>

#define B_ROWS 8192
#define D_DIM  128
#define NSLAB  8               // 8 column ranges of 1024 cols
#define STEPS  8               // 128-col steps per block

// zn8 rows are l2-normalized, scaled by SCALE = sqrt(2*log2(e)), quantized to
// fp8 e4m3. MFMA dot = 2*log2(e)*cos = log2(e^sim), sim = cos/tau, tau=0.5.
// exp2(acc) = e^sim <= e^2 (fp32-safe); pos = acc*ln2. (SCALE fold: R11-R13.)
#define SCALE  1.6986436f
#define LN2    0.69314718f

typedef __attribute__((ext_vector_type(2))) int   i32x2;
typedef __attribute__((ext_vector_type(4))) int   i32x4;
typedef __attribute__((ext_vector_type(4))) float f32x4;

typedef __attribute__((address_space(3))) uint32_t lds_u32;
typedef __attribute__((address_space(1))) const uint32_t glb_u32;

__device__ __forceinline__ float fast_exp2(float x) {
    float r;
    asm("v_exp_f32 %0, %1" : "=v"(r) : "v"(x));
    return r;
}

__device__ __forceinline__ long half64(i32x4 v, int h) {
    i32x2 p;
    p.x = h ? v.z : v.x;
    p.y = h ? v.w : v.y;
    return __builtin_bit_cast(long, p);
}

// ---------------- Kernel 1: l2-normalize rows, scale, quantize to fp8 -------
__global__ void k_norm(const float* __restrict__ z, uint8_t* __restrict__ zn8) {
    int row  = blockIdx.x * 4 + (threadIdx.x >> 6);
    int lane = threadIdx.x & 63;
    const float2 v = reinterpret_cast<const float2*>(z + (size_t)row * D_DIM)[lane];
    float ss = v.x * v.x + v.y * v.y;
    #pragma unroll
    for (int m = 1; m < 64; m <<= 1) ss += __shfl_xor(ss, m);
    float inv = SCALE * rsqrtf(fmaxf(ss, 1e-12f));
    __hip_fp8_e4m3 qx(v.x * inv);
    __hip_fp8_e4m3 qy(v.y * inv);
    unsigned short u = (unsigned short)qx.__x | ((unsigned short)qy.__x << 8);
    reinterpret_cast<unsigned short*>(zn8 + (size_t)row * D_DIM)[lane] = u;
}

// ---------------- Kernel 2: fp8 similarity + fused exp row-sums -------------
// R9's proven skeleton, fp8 data. 512 blocks (2/CU), 512 thr = 8 waves
// (4 row-groups x 2 col-halves), 16 waves/CU. Wave = 32 rows x 64 cols/step;
// step = 128 cols (16 KB fp8 tile) double-buffered in LDS; sync-per-step
// prefetch (R5/R9). MFMA = mfma_f32_16x16x32_fp8_fp8, K-chain 4.
// A and B use the IDENTICAL k-slot byte mapping (kp*64+lg*16+h*8), so any
// internal k-permutation cancels in the dot product.
__global__ __launch_bounds__(512, 4) void k_sim(const uint8_t* __restrict__ zn8,
                                                float* __restrict__ s_partial,
                                                float* __restrict__ pos) {
    __shared__ __align__(16) char sB[2][16384];
    __shared__ float red[128][2];

    const int tid  = threadIdx.x;
    const int lane = tid & 63;
    const int l15  = lane & 15;
    const int lg   = lane >> 4;          // 0..3
    const int w    = tid >> 6;           // 0..7
    const int wr   = w >> 1;             // 0..3 : rows [wr*32, +32)
    const int wc   = w & 1;              // 0..1 : cols [wc*64, +64) within step
    const int rb   = blockIdx.x >> 3;    // 0..63  (128-row tile)
    const int cr   = blockIdx.x & 7;     // 0..7   (1024-col range)
    const int R0   = rb * 128;
    const int C0   = cr * 1024;

    // stage one 128-col fp8 tile (16 KB): 2x 16B per thread, linear LDS dest,
    // inverse-XOR global source (involution u ^= col&7 on the 8 16B units)
    auto stage = [&](int gColBase, char* dst) {
        #pragma unroll
        for (int q = 0; q < 2; ++q) {
            int unit = q * 512 + tid;        // 0..1023
            int col  = unit >> 3;            // 0..127
            int u    = unit & 7;
            const uint8_t* g = zn8 + (size_t)(gColBase + col) * D_DIM
                                   + ((u ^ (col & 7)) << 4);
            __builtin_amdgcn_global_load_lds((glb_u32*)g, (lds_u32*)(dst + unit * 16), 16, 0, 0);
        }
    };

    stage(C0, sB[0]);                    // first tile in flight

    // ---- A fragments: global -> registers (2t x 2kp x 16B = 16 VGPR)
    // slot (kp,h): bytes kp*64 + lg*16 + h*8 of the row
    i32x4 afr[2][2];
    #pragma unroll
    for (int t = 0; t < 2; ++t)
        #pragma unroll
        for (int kp = 0; kp < 2; ++kp) {
            int row = R0 + wr * 32 + t * 16 + l15;
            afr[t][kp] = *reinterpret_cast<const i32x4*>(
                zn8 + (size_t)row * D_DIM + kp * 64 + lg * 16);
        }

    float srow[2][4];
    #pragma unroll
    for (int t = 0; t < 2; ++t)
        #pragma unroll
        for (int r = 0; r < 4; ++r) srow[t][r] = 0.f;

    __syncthreads();                     // tile 0 + A loads landed

    #pragma unroll 1
    for (int s = 0; s < STEPS; ++s) {
        if (s + 1 < STEPS)
            stage(C0 + (s + 1) * 128, sB[(s + 1) & 1]);   // prefetch next

        // B fragments: col c, unit g = kp*4+lg, swizzled b128 (2-way banks)
        const char* bb = sB[s & 1];
        i32x4 bfr[4][2];
        #pragma unroll
        for (int cs = 0; cs < 4; ++cs)
            #pragma unroll
            for (int kp = 0; kp < 2; ++kp) {
                int c = wc * 64 + cs * 16 + l15;
                bfr[cs][kp] = *reinterpret_cast<const i32x4*>(
                    bb + c * 128 + (((kp * 4 + lg) ^ (c & 7)) << 4));
            }

        #pragma unroll
        for (int t = 0; t < 2; ++t)
            #pragma unroll
            for (int cs = 0; cs < 4; ++cs) {
                f32x4 acc = {0.f, 0.f, 0.f, 0.f};
                #pragma unroll
                for (int kp = 0; kp < 2; ++kp)
                    #pragma unroll
                    for (int h = 0; h < 2; ++h)
                        acc = __builtin_amdgcn_mfma_f32_16x16x32_fp8_fp8(
                                half64(afr[t][kp], h), half64(bfr[cs][kp], h),
                                acc, 0, 0, 0);

                const int fragRow = R0 + wr * 32 + t * 16;
                const int fragCol = C0 + s * 128 + wc * 64 + cs * 16;
                if (fragRow == fragCol) {        // diagonal frag (wave-uniform)
                    const int col = fragCol + l15;
                    #pragma unroll
                    for (int r = 0; r < 4; ++r) {
                        int row = fragRow + lg * 4 + r;
                        float e = fast_exp2(acc[r]);                     // e^sim
                        if (col == row) e = 0.f;                         // self
                        if (col == (row ^ 1)) pos[row] = acc[r] * LN2;   // partner
                        srow[t][r] += e;
                    }
                } else {
                    #pragma unroll
                    for (int r = 0; r < 4; ++r)
                        srow[t][r] += fast_exp2(acc[r]);
                }
            }
        __syncthreads();   // prefetched tile landed; current buffer reusable
    }

    // ---- reduction: 16 lanes sharing a row -> cross-wave (wc) via LDS
    #pragma unroll
    for (int t = 0; t < 2; ++t)
        #pragma unroll
        for (int r = 0; r < 4; ++r) {
            float v = srow[t][r];
            v += __shfl_xor(v, 1);
            v += __shfl_xor(v, 2);
            v += __shfl_xor(v, 4);
            v += __shfl_xor(v, 8);
            if (l15 == 0) red[wr * 32 + t * 16 + lg * 4 + r][wc] = v;
        }
    __syncthreads();
    if (tid < 128)
        s_partial[(size_t)cr * B_ROWS + R0 + tid] = red[tid][0] + red[tid][1];
}

// ---------------- Kernel 3: fused per-row loss + final reduce (1 block) -----
__global__ __launch_bounds__(1024) void k_loss(const float* __restrict__ sp,
                                               const float* __restrict__ pos,
                                               float* __restrict__ out) {
    float acc = 0.f;
    #pragma unroll
    for (int b = 0; b < B_ROWS / 1024; ++b) {
        int i = b * 1024 + threadIdx.x;
        float ssum = 0.f;
        #pragma unroll
        for (int c = 0; c < NSLAB; ++c) ssum += sp[(size_t)c * B_ROWS + i];
        acc += logf(ssum) - pos[i];
    }
    #pragma unroll
    for (int m = 1; m < 64; m <<= 1) acc += __shfl_xor(acc, m);
    __shared__ float ls[16];
    if ((threadIdx.x & 63) == 0) ls[threadIdx.x >> 6] = acc;
    __syncthreads();
    if (threadIdx.x < 64) {
        float v = (threadIdx.x < 16) ? ls[threadIdx.x] : 0.f;
        #pragma unroll
        for (int m = 1; m < 16; m <<= 1) v += __shfl_xor(v, m);
        if (threadIdx.x == 0) out[0] = v * (1.0f / (float)B_ROWS);
    }
}

extern "C" void kernel_launch(void* const* d_in, const int* in_sizes, int n_in,
                              void* d_out, int out_size, void* d_ws, size_t ws_size,
                              hipStream_t stream) {
    const float* z = (const float*)d_in[0];
    float* out = (float*)d_out;

    char* ws = (char*)d_ws;
    uint8_t* zn8 = (uint8_t*)ws;                                           // 1 MB
    float* s_partial = (float*)(ws + (size_t)B_ROWS * D_DIM);              // 256 KB
    float* pos = (float*)((char*)s_partial + (size_t)NSLAB * B_ROWS * 4);  // 32 KB

    // 1) normalize + scale + fp8 quantize
    k_norm<<<B_ROWS / 4, 256, 0, stream>>>(z, zn8);

    // 2) fp8 similarity: 64 row-tiles x 8 col-ranges = 512 blocks (2/CU)
    k_sim<<<64 * NSLAB, 512, 0, stream>>>(zn8, s_partial, pos);

    // 3) fused per-row loss + mean (single block)
    k_loss<<<1, 1024, 0, stream>>>(s_partial, pos, out);
}